// Round 2
// baseline (968.239 us; speedup 1.0000x reference)
//
#include <hip/hip_runtime.h>
#include <math.h>

#define NPTS 4096
#define DIM 64
#define LOGW (-8.317766166719343f)   // -log(4096)
#define NEGINF (-__builtin_inff())

typedef __bf16 bf16x8 __attribute__((ext_vector_type(8)));
typedef float f32x4 __attribute__((ext_vector_type(4)));

static __device__ __forceinline__ f32x4 mfma16(bf16x8 a, bf16x8 b, f32x4 c) {
  return __builtin_amdgcn_mfma_f32_16x16x32_bf16(a, b, c, 0, 0, 0);
}

// ---------------------------------------------------------------------------
// Normalize rows to unit L2 norm and split into bf16 hi/lo pairs
// (v = hi + lo with |lo| <= 2^-9 |v| -> split-bf16 GEMM gives ~fp32 accuracy).
// One wave per row; grid 2048 x 256 covers 8192 rows (x then y).
// ---------------------------------------------------------------------------
__global__ __launch_bounds__(256) void norm_split_kernel(
    const float* __restrict__ x, const float* __restrict__ y,
    __bf16* __restrict__ xh, __bf16* __restrict__ xl,
    __bf16* __restrict__ yh, __bf16* __restrict__ yl) {
  int row  = blockIdx.x * 4 + (threadIdx.x >> 6);
  int lane = threadIdx.x & 63;
  const float* src; __bf16 *dh, *dl;
  if (row < NPTS) {
    src = x + (size_t)row * DIM; dh = xh + (size_t)row * DIM; dl = xl + (size_t)row * DIM;
  } else {
    int r = row - NPTS;
    src = y + (size_t)r * DIM; dh = yh + (size_t)r * DIM; dl = yl + (size_t)r * DIM;
  }
  float v = src[lane];
  float s = v * v;
  #pragma unroll
  for (int o = 32; o; o >>= 1) s += __shfl_xor(s, o, 64);
  v *= 1.0f / sqrtf(s);
  __bf16 h = (__bf16)v;
  __bf16 l = (__bf16)(v - (float)h);
  dh[lane] = h;
  dl[lane] = l;
}

// ---------------------------------------------------------------------------
// FUSED sweep: recompute cost tiles via split-bf16 MFMA and feed the fp32
// accumulator straight into an online row-logsumexp. The 128 MB cost matrix
// is never materialized (recompute = 3.2 us of MFMA/sweep vs 29 us of L3
// streaming to read it back; the 150 us cost-writing kernel disappears).
//
// Grid: 256 blocks (4 mats x 64 row-blocks), 256 threads (4 waves), 1/CU.
// Block = 64 A-rows x all 4096 B-cols; wave w owns cols [w*1024,(w+1)*1024).
// Per wave: 4 row-sets of 16 rows in A-frags (registers), 64 col-tiles,
// 6 MFMA per 16x16 tile (hi.hi k0,k1 + lo.hi k0,k1 + hi.lo k0,k1 -- same
// sequence as the old cost kernel). D-frag: col = L&15 (matches h index),
// row = (L>>4)*4 + q within the 16-row set.
//
// LSE: tv = h_j - max(1-dot,0)/eps = fma(min(dot,1), 1/eps, h_j - 1/eps).
// Per (row-set, q) accumulator: predicated defer-max (1 exp/element):
//   d = tv - m;  d > 8 ? { s = s*exp(-d) + 1; m = tv } : { s += exp(d) }
// s stays bounded (exp(d) <= e^8, 4096 terms < 1.3e7). m = -inf start takes
// the d>8 path on the first element. Exact: s = sum exp(tv_i - m) always.
// Merge: shfl_xor over the 16 col-lanes, then LDS merge across 4 waves.
// ---------------------------------------------------------------------------
__global__ __launch_bounds__(256, 1) void fused_pass_kernel(
    const __bf16* __restrict__ xh, const __bf16* __restrict__ xl,
    const __bf16* __restrict__ yh, const __bf16* __restrict__ yl,
    const float* __restrict__ potOld, float* __restrict__ potNew,
    float inv_eps, float eps, int use_pot, int avg) {
  __shared__ float hlds[NPTS];       // 16 KB: h[j] = LOGW + pot[j]/eps
  __shared__ float mred[4][64];
  __shared__ float sred[4][64];

  int mat = blockIdx.x >> 6;
  int rb  = blockIdx.x & 63;
  const __bf16 *Ah, *Al, *Bh, *Bl;
  if (mat == 0)      { Ah = xh; Al = xl; Bh = yh; Bl = yl; }
  else if (mat == 1) { Ah = yh; Al = yl; Bh = xh; Bl = xl; }
  else if (mat == 2) { Ah = xh; Al = xl; Bh = xh; Bl = xl; }
  else               { Ah = yh; Al = yl; Bh = yh; Bl = yl; }
  int ridx = (mat == 0) ? 1 : ((mat == 1) ? 0 : mat);
  const float* pot = potOld + (size_t)ridx * NPTS;

  // stage h[] into LDS (vectorized, 4 iters of float4 per thread)
  for (int j4 = threadIdx.x; j4 < NPTS / 4; j4 += 256) {
    float4 p;
    if (use_pot) {
      float4 q = *(const float4*)(pot + j4 * 4);
      p.x = fmaf(q.x, inv_eps, LOGW); p.y = fmaf(q.y, inv_eps, LOGW);
      p.z = fmaf(q.z, inv_eps, LOGW); p.w = fmaf(q.w, inv_eps, LOGW);
    } else {
      p.x = p.y = p.z = p.w = LOGW;
    }
    *(float4*)(hlds + j4 * 4) = p;
  }
  __syncthreads();

  int wave = threadIdx.x >> 6, L = threadIdx.x & 63;
  int mrow = L & 15, quad = L >> 4;
  int i0 = rb * 64;

  // A fragments for 4 row-sets (64 VGPRs, static indices only)
  bf16x8 Afh0[4], Afh1[4], Afl0[4], Afl1[4];
  #pragma unroll
  for (int r = 0; r < 4; ++r) {
    size_t ab = (size_t)(i0 + r * 16 + mrow) * DIM + quad * 8;
    Afh0[r] = *(const bf16x8*)(Ah + ab);
    Afh1[r] = *(const bf16x8*)(Ah + ab + 32);
    Afl0[r] = *(const bf16x8*)(Al + ab);
    Afl1[r] = *(const bf16x8*)(Al + ab + 32);
  }

  // online-LSE state: 16 (m,s) pairs, statically indexed
  float sm[16], ss[16];
  #pragma unroll
  for (int i = 0; i < 16; ++i) { sm[i] = NEGINF; ss[i] = 0.0f; }

  int jw = wave * 1024;
  // double-buffered B fragments (prefetch t+1 while computing t)
  size_t bb = (size_t)(jw + mrow) * DIM + quad * 8;
  bf16x8 b_h0 = *(const bf16x8*)(Bh + bb);
  bf16x8 b_h1 = *(const bf16x8*)(Bh + bb + 32);
  bf16x8 b_l0 = *(const bf16x8*)(Bl + bb);
  bf16x8 b_l1 = *(const bf16x8*)(Bl + bb + 32);
  float hh = hlds[jw + mrow];

  for (int t = 0; t < 64; ++t) {
    int tn = (t < 63) ? t + 1 : 63;
    size_t bbn = (size_t)(jw + tn * 16 + mrow) * DIM + quad * 8;
    bf16x8 n_h0 = *(const bf16x8*)(Bh + bbn);
    bf16x8 n_h1 = *(const bf16x8*)(Bh + bbn + 32);
    bf16x8 n_l0 = *(const bf16x8*)(Bl + bbn);
    bf16x8 n_l1 = *(const bf16x8*)(Bl + bbn + 32);
    float hhn = hlds[jw + tn * 16 + mrow];
    float hp = hh - inv_eps;

    #pragma unroll
    for (int r = 0; r < 4; ++r) {
      f32x4 acc = {0.0f, 0.0f, 0.0f, 0.0f};
      acc = mfma16(Afh0[r], b_h0, acc);
      acc = mfma16(Afh1[r], b_h1, acc);
      acc = mfma16(Afl0[r], b_h0, acc);
      acc = mfma16(Afl1[r], b_h1, acc);
      acc = mfma16(Afh0[r], b_l0, acc);
      acc = mfma16(Afh1[r], b_l1, acc);
      #pragma unroll
      for (int q = 0; q < 4; ++q) {
        // tv = h - max(1-dot,0)/eps
        float tv = fmaf(fminf(acc[q], 1.0f), inv_eps, hp);
        int id = r * 4 + q;
        float d = tv - sm[id];
        bool big = d > 8.0f;
        float e = __expf(big ? -d : d);
        ss[id] = big ? fmaf(ss[id], e, 1.0f) : (ss[id] + e);
        sm[id] = big ? tv : sm[id];
      }
    }
    b_h0 = n_h0; b_h1 = n_h1; b_l0 = n_l0; b_l1 = n_l1;
    hh = hhn;
  }

  // merge (m,s) across the 16 col-lanes of each quad group
  #pragma unroll
  for (int o = 1; o < 16; o <<= 1) {
    #pragma unroll
    for (int i = 0; i < 16; ++i) {
      float m2 = __shfl_xor(sm[i], o, 64);
      float s2 = __shfl_xor(ss[i], o, 64);
      float mn = fmaxf(sm[i], m2);
      ss[i] = ss[i] * __expf(sm[i] - mn) + s2 * __expf(m2 - mn);
      sm[i] = mn;
    }
  }

  // per-wave partials -> LDS (row = r*16 + quad*4 + q)
  if (mrow == 0) {
    #pragma unroll
    for (int r = 0; r < 4; ++r)
      #pragma unroll
      for (int q = 0; q < 4; ++q) {
        int row = r * 16 + quad * 4 + q;
        mred[wave][row] = sm[r * 4 + q];
        sred[wave][row] = ss[r * 4 + q];
      }
  }
  __syncthreads();

  // merge 4 waves (disjoint col ranges), finalize, write potential
  if (threadIdx.x < 64) {
    int row = threadIdx.x;
    float m = mred[0][row], s = sred[0][row];
    #pragma unroll
    for (int w = 1; w < 4; ++w) {
      float m2 = mred[w][row], s2 = sred[w][row];
      float mn = fmaxf(m, m2);
      s = s * __expf(m - mn) + s2 * __expf(m2 - mn);
      m = mn;
    }
    float ft = -eps * (m + __logf(s));
    float v = avg ? 0.5f * (potOld[(size_t)mat * NPTS + i0 + row] + ft) : ft;
    potNew[(size_t)mat * NPTS + i0 + row] = v;
  }
}

// ---------------------------------------------------------------------------
// out = mean(f_ba - f_aa) + mean(g_ab - g_bb), potentials at pot[0..3][NPTS]
// ---------------------------------------------------------------------------
__global__ __launch_bounds__(256) void final_kernel(
    const float* __restrict__ pot, float* __restrict__ out) {
  __shared__ float red[256];
  float s = 0.0f;
  for (int j = threadIdx.x; j < NPTS; j += 256)
    s += (pot[j] - pot[2 * NPTS + j]) + (pot[NPTS + j] - pot[3 * NPTS + j]);
  red[threadIdx.x] = s;
  __syncthreads();
  #pragma unroll
  for (int o = 128; o; o >>= 1) {
    if (threadIdx.x < o) red[threadIdx.x] += red[threadIdx.x + o];
    __syncthreads();
  }
  if (threadIdx.x == 0) out[0] = red[0] / (float)NPTS;
}

extern "C" void kernel_launch(void* const* d_in, const int* in_sizes, int n_in,
                              void* d_out, int out_size, void* d_ws, size_t ws_size,
                              hipStream_t stream) {
  const float* x = (const float*)d_in[0];
  const float* y = (const float*)d_in[1];
  char* ws = (char*)d_ws;

  // workspace layout (no cost matrix anymore: ~2.3 MB total)
  __bf16* xh = (__bf16*)ws;
  __bf16* xl = xh + (size_t)NPTS * DIM;
  __bf16* yh = xl + (size_t)NPTS * DIM;
  __bf16* yl = yh + (size_t)NPTS * DIM;
  float* potA = (float*)(yl + (size_t)NPTS * DIM);    // 4 * NPTS
  float* potB = potA + 4 * (size_t)NPTS;
  size_t needed = (size_t)((char*)(potB + 4 * (size_t)NPTS) - ws);
  if (ws_size < needed) return;

  norm_split_kernel<<<2048, 256, 0, stream>>>(x, y, xh, xl, yh, yl);

  // geomloss epsilon schedule (p=2, blur=0.05, scaling=0.8, diameter=2)
  double lst[32];
  int c = 0;
  lst[c++] = 4.0;
  double start = 2.0 * log(2.0), stop = 2.0 * log(0.05), step = 2.0 * log(0.8);
  for (int k = 0;; ++k) {
    double v = start + (double)k * step;
    if (v <= stop) break;
    lst[c++] = exp(v);
  }
  lst[c++] = 0.05 * 0.05;   // c == 19

  // sweeps: p=0 init (no pot, assign); p=1..c loop (avg); p=c+1 final (assign)
  for (int p = 0; p < c + 2; ++p) {
    double e = (p == 0) ? lst[0] : ((p <= c) ? lst[p - 1] : lst[c - 1]);
    float eps = (float)e;
    float inv_eps = 1.0f / eps;
    int use_pot = (p > 0) ? 1 : 0;
    int avg = (p >= 1 && p <= c) ? 1 : 0;
    const float* po = (p & 1) ? potB : potA;
    float* pn       = (p & 1) ? potA : potB;
    fused_pass_kernel<<<256, 256, 0, stream>>>(xh, xl, yh, yl, po, pn,
                                               inv_eps, eps, use_pot, avg);
  }
  // c+2 = 21 sweeps; last sweep (p=20, even) wrote potB
  final_kernel<<<1, 256, 0, stream>>>(potB, (float*)d_out);
}